// Round 8
// baseline (410.386 us; speedup 1.0000x reference)
//
#include <hip/hip_runtime.h>
#include <hip/hip_cooperative_groups.h>
#include <math.h>

namespace cg = cooperative_groups;

typedef _Float16 h8 __attribute__((ext_vector_type(8)));
typedef float    f4v __attribute__((ext_vector_type(4)));

#define N_TRAIN 400000
#define DIMS    27
#define BQ      512
#define NCLS    11
#define KNN     3
#define NB      250            // blocks: <= 256 CUs -> co-resident at just 1 block/CU
#define P1T     1024           // threads (16 waves)
#define PTS_BLK 1600           // points per block (250*1600 = 400000 exact)
#define PTS_SUP 160            // points per super-tile
#define NSUP    10             // super-tiles per block
#define NPT     10             // ptiles per super-tile (tiles/block = 100, fits 7 bits)
#define RAWF    4320           // floats per super-tile (160*27)
#define TILE_B  2048           // conv bytes per ptile: hi 1024 + lo 1024
#define NC      (NB * KNN)     // candidates per query (750)

#define U64MAX 0xFFFFFFFFFFFFFFFFULL

// lexicographic (key, idx) insert into ascending sorted triple — matches top_k ties
__device__ __forceinline__ void insert3(float d, int i, float* bd, int* bi) {
    if (d < bd[2] || (d == bd[2] && i < bi[2])) {
        if (d < bd[1] || (d == bd[1] && i < bi[1])) {
            bd[2] = bd[1]; bi[2] = bi[1];
            if (d < bd[0] || (d == bd[0] && i < bi[0])) {
                bd[1] = bd[0]; bi[1] = bi[0];
                bd[0] = d; bi[0] = i;
            } else { bd[1] = d; bi[1] = i; }
        } else { bd[2] = d; bi[2] = i; }
    }
}

// 64-bit xor-shuffle via two 32-bit shuffles
__device__ __forceinline__ unsigned long long shfl_xor_u64(unsigned long long v, int m) {
    unsigned lo = (unsigned)v, hi = (unsigned)(v >> 32);
    lo = __shfl_xor(lo, m, 64);
    hi = __shfl_xor(hi, m, 64);
    return ((unsigned long long)hi << 32) | lo;
}

// branchless insert into ascending sorted-3 of u64 (keep 3 smallest)
__device__ __forceinline__ void ins3u64(unsigned long long e,
                                        unsigned long long& t0,
                                        unsigned long long& t1,
                                        unsigned long long& t2) {
    unsigned long long a  = e < t2 ? e : t2;
    unsigned long long n2 = t1 > a ? t1 : a;
    unsigned long long n1 = t1 < a ? t1 : a;
    t2 = n2;
    unsigned long long m1 = t0 > n1 ? t0 : n1;
    t0 = t0 < n1 ? t0 : n1;
    t1 = m1;
}

// branchless compare-exchange (ascending)
#define CE(a, b) do { unsigned long long lo_ = (a) < (b) ? (a) : (b); \
                      unsigned long long hi_ = (a) < (b) ? (b) : (a); \
                      (a) = lo_; (b) = hi_; } while (0)

__device__ __forceinline__ void stage16(const float* g, float* l) {
    __builtin_amdgcn_global_load_lds((const __attribute__((address_space(1))) void*)g,
                                     (__attribute__((address_space(3))) void*)l, 16, 0, 0);
}

// ================= phase S: per-block max|row| over own 1600 rows -> partial =================
// uint4 4-row groups (g*432 bytes, 16B aligned); column (4k+e)%27 is compile-time (rule #20).
__device__ __forceinline__ void phaseS(const float* __restrict__ train,
                                       float* __restrict__ partial,
                                       int bid, int tid, float* redS) {
    int lane = tid & 63, w = tid >> 6;
    float m[DIMS];
#pragma unroll
    for (int d = 0; d < DIMS; ++d) m[d] = 0.f;
    if (tid < PTS_BLK / 4) {                       // 400 groups of 4 rows
        int g = bid * (PTS_BLK / 4) + tid;
        const uint4* p = (const uint4*)(train + (size_t)g * (4 * DIMS));
#pragma unroll
        for (int k = 0; k < DIMS; ++k) {
            uint4 v = p[k];
            m[(4 * k + 0) % DIMS] = fmaxf(m[(4 * k + 0) % DIMS], fabsf(__uint_as_float(v.x)));
            m[(4 * k + 1) % DIMS] = fmaxf(m[(4 * k + 1) % DIMS], fabsf(__uint_as_float(v.y)));
            m[(4 * k + 2) % DIMS] = fmaxf(m[(4 * k + 2) % DIMS], fabsf(__uint_as_float(v.z)));
            m[(4 * k + 3) % DIMS] = fmaxf(m[(4 * k + 3) % DIMS], fabsf(__uint_as_float(v.w)));
        }
    }
#pragma unroll
    for (int d = 0; d < DIMS; ++d) {               // wave butterfly (27 dims x 6 steps)
        float t = m[d];
#pragma unroll
        for (int st = 1; st < 64; st <<= 1) t = fmaxf(t, __shfl_xor(t, st, 64));
        m[d] = t;
    }
    if (lane == 0) {
#pragma unroll
        for (int d = 0; d < DIMS; ++d) redS[w * 32 + d] = m[d];
    }
    __syncthreads();
    if (tid < 32) {
        float v = 0.f;
        if (tid < DIMS) {
#pragma unroll
            for (int g2 = 0; g2 < 16; ++g2) v = fmaxf(v, redS[g2 * 32 + tid]);
        }
        partial[bid * 32 + tid] = v;               // dims 27..31 = 0 (fully written, no memset)
    }
    __threadfence();
}

// reduce NB x 32 partials -> s_inv (exact same values as the old atomicMax path)
__device__ __forceinline__ void scale_reduce(const float* __restrict__ partial,
                                             float* redP, float* s_inv, int tid) {
    if (tid < 512) {
        int d = tid & 31, ch = tid >> 5;           // 16 chunks
        float v = 0.f;
        for (int b = ch; b < NB; b += 16) v = fmaxf(v, partial[b * 32 + d]);
        redP[ch * 32 + d] = v;
    }
    __syncthreads();
    if (tid < 32) {
        float sc = 0.f;
#pragma unroll
        for (int g2 = 0; g2 < 16; ++g2) sc = fmaxf(sc, redP[g2 * 32 + tid]);
        s_inv[tid] = (sc != 0.f) ? 1.f / sc : 0.f; // divide_no_nan; 0 for d>=27
    }
}

// conv: task = (point p, kblock gq of 8 dims); 640 tasks, waves 10..15 skip
__device__ __forceinline__ void conv_tile(const float* rw, unsigned char* dst0,
                                          int tid, const float* s_inv) {
    if (tid < PTS_SUP * 4) {
        int p = tid >> 2, gq = tid & 3;
        float x[8]; float part = 0.f;
#pragma unroll
        for (int i = 0; i < 8; ++i) {
            int d = gq * 8 + i;
            int dc = d < DIMS ? d : (DIMS - 1);    // clamp; s_inv[d>=27]=0 zeroes value
            float v = rw[p * DIMS + dc] * s_inv[d];
            x[i] = v;
            part = fmaf(v, v, part);
        }
        part += __shfl_xor(part, 1, 64);
        part += __shfl_xor(part, 2, 64);           // all 4 kblock-lanes hold xn
        h8 hv, lv;
#pragma unroll
        for (int i = 0; i < 8; ++i) {
            _Float16 h = (_Float16)x[i];
            hv[i] = h;
            lv[i] = (_Float16)(x[i] - (float)h);
        }
        if (gq == 3) {                             // slot i=3 is k=27: -xn/2 split
            float tt = -0.5f * part;
            _Float16 th = (_Float16)tt;
            hv[3] = th;
            lv[3] = (_Float16)(tt - (float)th);
        }
        unsigned char* dstb = dst0 + (p >> 4) * TILE_B + gq * 256 + (p & 15) * 16;
        *(h8*)dstb = hv;
        *(h8*)(dstb + 1024) = lv;
    }
}

// compute one super-tile: 10 ptiles x 2 query-tiles x 3 MFMA + u32 top-2 update (7-bit tile)
__device__ __forceinline__ void compute_super(const unsigned char* cb, int ss, int lane,
                                              const h8* bhi, const h8* blo,
                                              unsigned kb0[2][4], unsigned kb1[2][4]) {
    const f4v z4 = {64.f, 64.f, 64.f, 64.f};       // +64 bias rides through MFMA C
    for (int t = 0; t < NPT; ++t) {
        const unsigned char* basep = cb + t * TILE_B;
        h8 ahi = *(const h8*)(basep + lane * 16);  // lane-linear: conflict-free
        h8 alo = *(const h8*)(basep + 1024 + lane * 16);
        unsigned ic = 127u - (unsigned)(ss * NPT + t);  // wave-uniform tile code, 7 bits
#pragma unroll
        for (int j = 0; j < 2; ++j) {
            f4v acc;
            acc = __builtin_amdgcn_mfma_f32_16x16x32_f16(alo, bhi[j], z4, 0, 0, 0);
            acc = __builtin_amdgcn_mfma_f32_16x16x32_f16(ahi, blo[j], acc, 0, 0, 0);
            acc = __builtin_amdgcn_mfma_f32_16x16x32_f16(ahi, bhi[j], acc, 0, 0, 0);
#pragma unroll
            for (int r = 0; r < 4; ++r) {
                unsigned key = (__float_as_uint(acc[r]) & 0xFFFFFF80u) | ic;  // v_and_or_b32
                unsigned b0 = kb0[j][r];
                unsigned m  = key < b0 ? key : b0;  // v_min_u32
                kb0[j][r]   = key > b0 ? key : b0;  // v_max_u32
                unsigned b1 = kb1[j][r];
                kb1[j][r]   = m > b1 ? m : b1;      // v_max_u32
            }
        }
    }
}

// ================= phase P1: staged/pipelined MFMA scan -> per-block top-3 per query =================
__device__ __forceinline__ void phaseP1(const float* __restrict__ train,
                                        const float* __restrict__ query,
                                        const float* __restrict__ partial,
                                        unsigned long long* __restrict__ cand,
                                        int bid, int tid,
                                        float* s_inv, float* rawb, unsigned char* convbb,
                                        float* redP) {
    int lane = tid & 63, w = tid >> 6;
    int l15 = lane & 15, quad = lane >> 4;
    int p0 = bid * PTS_BLK;
    const float* gsup = train + (size_t)p0 * DIMS; // 16B aligned (1600*108 % 16 == 0)

    {   // stage super-tile 0 (async; flies during scale reduce)
        const float* gp = gsup; float* lp = rawb;
        stage16(gp + tid * 4, lp + tid * 4);
        if (tid < 56) stage16(gp + 4096 + tid * 4, lp + 4096 + tid * 4);
    }
    scale_reduce(partial, redP, s_inv, tid);       // internal barrier also drains stage(0)

    unsigned kb0[2][4], kb1[2][4];                 // top-2 keys per (j, r); 0 = -inf sentinel
#pragma unroll
    for (int j = 0; j < 2; ++j)
#pragma unroll
        for (int r = 0; r < 4; ++r) { kb0[j][r] = 0u; kb1[j][r] = 0u; }

    __syncthreads();   // barrier A: s_inv visible; raw[0] ready

    {   // stage super-tile 1
        const float* gp = gsup + RAWF; float* lp = rawb + RAWF;
        stage16(gp + tid * 4, lp + tid * 4);
        if (tid < 56) stage16(gp + 4096 + tid * 4, lp + 4096 + tid * 4);
    }
    conv_tile(rawb, convbb, tid, s_inv);           // conv(0)

    h8 bhi[2], blo[2];                             // in-register qprep (same op order as verified)
#pragma unroll
    for (int j = 0; j < 2; ++j) {
        int q = (w * 2 + j) * 16 + l15;            // query 0..511
        const float* qr = query + (size_t)q * DIMS;
#pragma unroll
        for (int i = 0; i < 8; ++i) {
            int d = quad * 8 + i;
            int dc = d < DIMS ? d : (DIMS - 1);
            float xs = qr[dc] * s_inv[d];
            _Float16 hi = (_Float16)xs;
            _Float16 lo = (_Float16)(xs - (float)hi);
            bool is27 = (d == 27);
            bhi[j][i] = is27 ? (_Float16)1.f : hi; // k=27 slot multiplies A's -xn/2
            blo[j][i] = is27 ? (_Float16)0.f : lo;
        }
    }

    for (int s = 1; s < NSUP; ++s) {               // barrier, stage(s+1), conv(s), compute(s-1)
        __syncthreads();
        if (s + 1 < NSUP) {
            const float* gp = gsup + (size_t)(s + 1) * RAWF;
            float* lp = rawb + ((s + 1) & 1) * RAWF;
            stage16(gp + tid * 4, lp + tid * 4);
            if (tid < 56) stage16(gp + 4096 + tid * 4, lp + 4096 + tid * 4);
        }
        conv_tile(rawb + (s & 1) * RAWF, convbb + (s & 1) * (NPT * TILE_B), tid, s_inv);
        compute_super(convbb + ((s - 1) & 1) * (NPT * TILE_B), s - 1, lane, bhi, blo, kb0, kb1);
    }
    __syncthreads();
    compute_super(convbb + ((NSUP - 1) & 1) * (NPT * TILE_B), NSUP - 1, lane, bhi, blo, kb0, kb1);

    // decode + cross-quad merge -> block top-3 per query -> cand
    int qr4 = quad * 4;
#pragma unroll
    for (int j = 0; j < 2; ++j) {
        unsigned long long t0 = U64MAX, t1 = U64MAX, t2 = U64MAX;
#pragma unroll
        for (int r = 0; r < 4; ++r) {
#pragma unroll
            for (int h = 0; h < 2; ++h) {
                unsigned k = h ? kb1[j][r] : kb0[j][r];
                unsigned tile = 127u - (k & 127u);
                unsigned gi = (unsigned)(p0 + (int)tile * 16 + qr4 + r);
                unsigned long long e = ((unsigned long long)(~(k | 127u)) << 32) | gi;
                ins3u64(e, t0, t1, t2);
            }
        }
#pragma unroll
        for (int step = 16; step <= 32; step <<= 1) {
            unsigned long long o0 = shfl_xor_u64(t0, step);
            unsigned long long o1 = shfl_xor_u64(t1, step);
            unsigned long long o2 = shfl_xor_u64(t2, step);
            ins3u64(o0, t0, t1, t2);
            ins3u64(o1, t0, t1, t2);
            ins3u64(o2, t0, t1, t2);
        }
        if (quad == 0) {
            int qq = (w * 2 + j) * 16 + l15;
            size_t off = (size_t)qq * NC + (size_t)bid * KNN;
            cand[off + 0] = t0; cand[off + 1] = t1; cand[off + 2] = t2;
        }
    }
    __threadfence();
}

// ================= phase P2: u64 top-8 merge -> exact f32 refine -> vote =================
__device__ __forceinline__ void phaseP2(const unsigned long long* __restrict__ cand,
                                        const float* __restrict__ train,
                                        const float* __restrict__ query,
                                        const float* __restrict__ labels,
                                        float* __restrict__ out,
                                        int bid, int tid,
                                        const float* s_inv, unsigned long long* smerge) {
    int lane = tid & 63, w = tid >> 6;
    for (int q = bid; q < BQ; q += NB) {           // blocks 0..11 handle 3 queries, rest 2
        const unsigned long long* cd = cand + (size_t)q * NC;
        unsigned long long c0 = (tid < NC) ? cd[tid] : U64MAX;   // 1 candidate/thread (750<=1024)
#pragma unroll
        for (int k = 0; k < 8; ++k) {              // per-wave top-8 by butterfly-min extraction
            unsigned long long m = c0;
#pragma unroll
            for (int st = 1; st < 64; st <<= 1) {
                unsigned long long o = shfl_xor_u64(m, st);
                if (o < m) m = o;
            }
            if (lane == 0) smerge[w * 8 + k] = m;
            c0 = (c0 == m) ? U64MAX : c0;          // unique pop (distinct idx); all-MAX waves benign
        }
        __syncthreads();

        if (w == 0) {
            // merge 128 wave winners -> global top-8; lane k keeps idx of rank k
            int myi = 0x7fffffff;
            unsigned long long e0 = smerge[lane], e1 = smerge[64 + lane];
            CE(e0, e1);
#pragma unroll
            for (int k = 0; k < 8; ++k) {
                unsigned long long m = e0;
#pragma unroll
                for (int st = 1; st < 64; st <<= 1) {
                    unsigned long long o = shfl_xor_u64(m, st);
                    if (o < m) m = o;
                }
                if (lane == k) myi = (int)(unsigned)m;
                bool win = (e0 == m);
                e0 = win ? e1 : e0;
                e1 = win ? U64MAX : e1;
            }

            // exact refine — same op order as the verified path
            float qn_ = 0.f;
#pragma unroll
            for (int d = 0; d < DIMS; ++d) {
                float v = query[(size_t)q * DIMS + d] * s_inv[d];
                qn_ = fmaf(v, v, qn_);
            }
            float myd2 = 3.4e38f;
            if (lane < 8) {
                const float* r = train + (size_t)myi * DIMS;
                float xnv = 0.f, dot = 0.f;
#pragma unroll
                for (int d = 0; d < DIMS; ++d) {
                    float iv = s_inv[d];
                    float qv = query[(size_t)q * DIMS + d] * iv;
                    float tv = r[d] * iv;
                    xnv = fmaf(tv, tv, xnv);
                    dot = fmaf(qv, tv, dot);
                }
                myd2 = fmaf(-2.f, dot, qn_ + xnv);
            }

            float bd[KNN] = {3.4e38f, 3.4e38f, 3.4e38f};
            int   bi[KNN] = {0x7fffffff, 0x7fffffff, 0x7fffffff};
#pragma unroll
            for (int k = 0; k < 8; ++k) {
                float dk = __shfl(myd2, k, 64);
                int   ik = __shfl(myi, k, 64);
                insert3(dk, ik, bd, bi);
            }

            if (lane == 0) {
                float kd[KNN];
#pragma unroll
                for (int k = 0; k < KNN; ++k) kd[k] = sqrtf(fmaxf(bd[k], 0.f));
                float votes[NCLS];
#pragma unroll
                for (int c = 0; c < NCLS; ++c) votes[c] = 0.f;
#pragma unroll
                for (int k = 0; k < KNN; ++k) {
                    float ks = (kd[k] == 0.f) ? 1.f : kd[k];
                    const float* lr = labels + (size_t)bi[k] * NCLS;
#pragma unroll
                    for (int c = 0; c < NCLS; ++c) votes[c] += lr[c] / ks;
                }
                int best = 0; float bv = votes[0];
#pragma unroll
                for (int c = 1; c < NCLS; ++c) { if (votes[c] > bv) { bv = votes[c]; best = c; } }
                bool zero_hit = (kd[0] == 0.f);
#pragma unroll
                for (int k = 0; k < KNN; ++k) out[(size_t)q * KNN + k] = kd[k];
                const float* l0 = labels + (size_t)bi[0] * NCLS;
                float* ro = out + (size_t)BQ * KNN + (size_t)q * NCLS;
#pragma unroll
                for (int c = 0; c < NCLS; ++c)
                    ro[c] = zero_hit ? l0[c] : ((c == best) ? 1.f : 0.f);
            }
        }
        __syncthreads();                           // smerge reuse guard between q iterations
    }
}

// ---------------- mega kernel (cooperative): S -> sync -> P1 -> sync -> P2 ----------------
__global__ __attribute__((amdgpu_flat_work_group_size(P1T, P1T)))
__attribute__((amdgpu_waves_per_eu(4)))
void k_mega(const float* __restrict__ train,
            const float* __restrict__ query,
            const float* __restrict__ labels,
            float* __restrict__ partial,
            unsigned long long* __restrict__ cand,
            float* __restrict__ out) {
    __shared__ float s_inv[32];
    __shared__ __align__(16) float raw[2][RAWF];                     // 34560 B
    __shared__ __align__(16) unsigned char convb[2][NPT * TILE_B];   // 40960 B
    // phase-local scratch aliased into convb (disjoint lifetimes, sync-separated):
    float* redS = (float*)&convb[0][0];                              // [16][32] phase S
    float* redP = (float*)&convb[0][4096];                           // [16][32] scale reduce
    unsigned long long* smerge = (unsigned long long*)&convb[0][8192]; // [128] phase P2

    int tid = threadIdx.x, bid = blockIdx.x;
    phaseS(train, partial, bid, tid, redS);
    cg::this_grid().sync();
    phaseP1(train, query, partial, cand, bid, tid, s_inv, &raw[0][0], &convb[0][0], redP);
    cg::this_grid().sync();
    phaseP2(cand, train, query, labels, out, bid, tid, s_inv, smerge);
}

// ---------------- non-cooperative fallback: same phases as 3 kernels ----------------
__global__ __attribute__((amdgpu_flat_work_group_size(P1T, P1T)))
void k_scale_f(const float* __restrict__ train, float* __restrict__ partial) {
    __shared__ float redS[16 * 32];
    phaseS(train, partial, blockIdx.x, threadIdx.x, redS);
}

__global__ __attribute__((amdgpu_flat_work_group_size(P1T, P1T)))
__attribute__((amdgpu_waves_per_eu(4)))
void k_p1_f(const float* __restrict__ train, const float* __restrict__ query,
            const float* __restrict__ partial, unsigned long long* __restrict__ cand) {
    __shared__ float s_inv[32];
    __shared__ __align__(16) float raw[2][RAWF];
    __shared__ __align__(16) unsigned char convb[2][NPT * TILE_B];
    float* redP = (float*)&convb[0][4096];
    phaseP1(train, query, partial, cand, blockIdx.x, threadIdx.x,
            s_inv, &raw[0][0], &convb[0][0], redP);
}

__global__ __attribute__((amdgpu_flat_work_group_size(P1T, P1T)))
void k_p2_f(const unsigned long long* __restrict__ cand, const float* __restrict__ train,
            const float* __restrict__ query, const float* __restrict__ labels,
            const float* __restrict__ partial, float* __restrict__ out) {
    __shared__ float s_inv[32];
    __shared__ float redP[512];
    __shared__ unsigned long long smerge[128];
    scale_reduce(partial, redP, s_inv, threadIdx.x);
    __syncthreads();
    phaseP2(cand, train, query, labels, out, blockIdx.x, threadIdx.x, s_inv, smerge);
}

extern "C" void kernel_launch(void* const* d_in, const int* in_sizes, int n_in,
                              void* d_out, int out_size, void* d_ws, size_t ws_size,
                              hipStream_t stream) {
    const float* query  = (const float*)d_in[0];
    const float* train  = (const float*)d_in[1];
    const float* labels = (const float*)d_in[2];
    float* out = (float*)d_out;

    // ws layout:
    //   [0)      partial: 250*32 f32 (32000 B, fully written -> no memset)
    //   [32768)  cand: 512*750 u64 (3072000 B)
    char* ws = (char*)d_ws;
    float* partial = (float*)ws;
    unsigned long long* cand = (unsigned long long*)(ws + 32768);

    void* args[] = { (void*)&train, (void*)&query, (void*)&labels,
                     (void*)&partial, (void*)&cand, (void*)&out };
    hipError_t err = hipLaunchCooperativeKernel((const void*)k_mega, dim3(NB), dim3(P1T),
                                                args, 0, stream);
    if (err != hipSuccess) {
        // fallback: identical phases as ordinary kernels (correct regardless of coop support)
        k_scale_f<<<NB, P1T, 0, stream>>>(train, partial);
        k_p1_f<<<NB, P1T, 0, stream>>>(train, query, partial, cand);
        k_p2_f<<<NB, P1T, 0, stream>>>(cand, train, query, labels, partial, out);
    }
}